// Round 1
// baseline (1290.377 us; speedup 1.0000x reference)
//
#include <hip/hip_runtime.h>
#include <math.h>

#define H 4096
#define E 64
#define TOPK 8
#define NSLICE 16            // K split across blocks: grid = (T/64)*16 = 4096 -> 16 waves/CU
#define KS (H / NSLICE)      // 256
#define TAU 1e-4f            // f32 rank-ambiguity threshold (f32 err ~3e-6 rms, 2e-5 worst)

// Fused MoE router, restructured:
//   k0: W[E][H] -> Wt[H][E] (workspace) so Wt[k][e] rows are wave-uniform-loadable
//   k1: f32 outer-product GEMM: lane=row, acc[64] experts, W broadcast via SGPR
//       (s_load) -> zero LDS / zero barriers / zero f64. K sliced 16x across
//       blocks, f32 atomicAdd into pre-zeroed probs buffer.
//   k2: +bias, sigmoid (in-place), register-resident top-9, flag rows whose
//       adjacent top-9 logit gaps < TAU (f32 order not provably == f64 order).
//   k3: exact-f64 recompute of flagged rows (~100-300 expected), overwrite
//       weights/indices. Harness checks indices vs f64 reference; unflagged
//       rows have gaps >> f32 error so f32 order is exact.
// Workspace layout: [0,1MiB) Wt ; [1MiB] flag count ; [1MiB+16, ...) flag list.

// ---------------- kernel 0: transpose W -> Wt ----------------
__global__ __launch_bounds__(256) void wt_transpose(
    const float* __restrict__ W, float* __restrict__ Wt)
{
    const int t  = blockIdx.x * 256 + threadIdx.x;   // 65536 threads, 4 elems each
    const int k  = t >> 4;                           // 0..4095
    const int e0 = (t & 15) * 4;
    float4 v;
    v.x = W[(e0 + 0) * H + k];
    v.y = W[(e0 + 1) * H + k];
    v.z = W[(e0 + 2) * H + k];
    v.w = W[(e0 + 3) * H + k];
    *(float4*)(Wt + k * E + e0) = v;
}

// ---------------- kernel 1: f32 slice GEMM, SGPR-broadcast W ----------------
// 64-thread (1-wave) blocks; lane = row. Wt addresses depend only on
// blockIdx/loop counter -> uniform -> s_load_dwordx16; FMA reads 1 SGPR + VGPR.
__global__ __launch_bounds__(64, 4) void router_gemm(
    const float* __restrict__ A, const float* __restrict__ Wt,
    float* __restrict__ logits)
{
    const int ks = blockIdx.x & (NSLICE - 1);
    const int rg = blockIdx.x >> 4;
    const int k0 = ks * KS;
    const long row = (long)rg * 64 + threadIdx.x;

    float acc[E];
#pragma unroll
    for (int e = 0; e < E; ++e) acc[e] = 0.0f;

    const float* __restrict__ ap = A + row * H + k0;
    const float* __restrict__ wp = Wt + (long)k0 * E;

#pragma unroll 2
    for (int k = 0; k < KS; k += 4) {
        const float4 av = *(const float4*)(ap + k);   // per-lane own row, L1-friendly
        const float* __restrict__ w0 = wp + (k + 0) * E;
        const float* __restrict__ w1 = wp + (k + 1) * E;
        const float* __restrict__ w2 = wp + (k + 2) * E;
        const float* __restrict__ w3 = wp + (k + 3) * E;
#pragma unroll
        for (int e = 0; e < E; ++e) acc[e] = fmaf(av.x, w0[e], acc[e]);
#pragma unroll
        for (int e = 0; e < E; ++e) acc[e] = fmaf(av.y, w1[e], acc[e]);
#pragma unroll
        for (int e = 0; e < E; ++e) acc[e] = fmaf(av.z, w2[e], acc[e]);
#pragma unroll
        for (int e = 0; e < E; ++e) acc[e] = fmaf(av.w, w3[e], acc[e]);
    }

    float* out = logits + row * E;   // probs buffer, pre-zeroed; device-scope f32 add
#pragma unroll
    for (int e = 0; e < E; ++e) atomicAdd(out + e, acc[e]);
}

// ---------------- kernel 2: bias + sigmoid + top-9 + ambiguity flag ----------------
// All per-thread arrays indexed with compile-time constants only (no scratch).
__global__ __launch_bounds__(64) void router_topk(
    float* __restrict__ probs, const float* __restrict__ bias,
    float* __restrict__ weights, float* __restrict__ indices,
    int* __restrict__ flagcnt, int* __restrict__ flaglist, int cap)
{
    const long row = (long)blockIdx.x * 64 + threadIdx.x;
    float* pr = probs + row * E;

    float lg[E];
#pragma unroll
    for (int e = 0; e < E; e += 4) {
        const float4 v = *(const float4*)(pr + e);
        const float4 b = *(const float4*)(bias + e);
        lg[e + 0] = v.x + b.x;
        lg[e + 1] = v.y + b.y;
        lg[e + 2] = v.z + b.z;
        lg[e + 3] = v.w + b.w;
    }

    // overwrite raw logit sums with final sigmoid probs (same thread owns row)
#pragma unroll
    for (int e = 0; e < E; e += 4) {
        float4 o;
        o.x = 1.0f / (1.0f + __expf(-lg[e + 0]));
        o.y = 1.0f / (1.0f + __expf(-lg[e + 1]));
        o.z = 1.0f / (1.0f + __expf(-lg[e + 2]));
        o.w = 1.0f / (1.0f + __expf(-lg[e + 3]));
        *(float4*)(pr + e) = o;
    }

    // top-9 selection on logits; strict > => lowest index wins ties
    unsigned long long taken = 0ull;
    float sv[TOPK + 1];
    int   si[TOPK + 1];
#pragma unroll
    for (int it = 0; it <= TOPK; ++it) {
        float best = -3.0e38f;
        int   bi   = 0;
#pragma unroll
        for (int j = 0; j < E; ++j) {
            const bool ok = !((taken >> j) & 1ull) && (lg[j] > best);
            best = ok ? lg[j] : best;
            bi   = ok ? j   : bi;
        }
        sv[it] = best;
        si[it] = bi;
        taken |= 1ull << bi;
    }

    float w8[TOPK];
    float sum = 0.0f;
#pragma unroll
    for (int it = 0; it < TOPK; ++it) {
        w8[it] = 1.0f / (1.0f + __expf(-sv[it]));
        sum += w8[it];
    }
    const float inv = 1.0f / sum;
#pragma unroll
    for (int it = 0; it < TOPK; ++it) {
        weights[row * TOPK + it] = w8[it] * inv;
        indices[row * TOPK + it] = (float)si[it];
    }

    // rank order provable only if every adjacent gap (ranks 1-2 .. 8-9) > TAU
    bool amb = false;
#pragma unroll
    for (int it = 0; it < TOPK; ++it) amb |= (sv[it] - sv[it + 1]) < TAU;
    if (amb && cap > 0) {
        const int pos = atomicAdd(flagcnt, 1);
        if (pos < cap) flaglist[pos] = (int)row;
    }
}

// ---------------- kernel 3: exact-f64 recheck of flagged rows ----------------
__global__ __launch_bounds__(256) void router_recheck(
    const float* __restrict__ A, const float* __restrict__ W,
    const float* __restrict__ bias,
    float* __restrict__ weights, float* __restrict__ indices,
    const int* __restrict__ flagcnt, const int* __restrict__ flaglist,
    int cap)
{
    __shared__ double part[4][E];
    __shared__ double lg[E];

    const int e  = threadIdx.x & 63;   // expert
    const int kc = threadIdx.x >> 6;   // k-chunk 0..3 (1024 each)

    int n = *flagcnt;
    if (n > cap) n = cap;

    for (int f = blockIdx.x; f < n; f += gridDim.x) {
        const int row = flaglist[f];
        const float* ar = A + (long)row * H + kc * (H / 4);
        const float* wr = W + (long)e   * H + kc * (H / 4);
        double s = 0.0;
        for (int k = 0; k < H / 4; k += 4) {
            const float4 av = *(const float4*)(ar + k);   // broadcast across lanes
            const float4 wv = *(const float4*)(wr + k);   // W hot in L2
            s = fma((double)av.x, (double)wv.x, s);
            s = fma((double)av.y, (double)wv.y, s);
            s = fma((double)av.z, (double)wv.z, s);
            s = fma((double)av.w, (double)wv.w, s);
        }
        part[kc][e] = s;
        __syncthreads();
        if (threadIdx.x < E) {
            const int j = threadIdx.x;
            lg[j] = ((part[0][j] + part[1][j]) + (part[2][j] + part[3][j]))
                    + (double)bias[j];
        }
        __syncthreads();
        if (threadIdx.x == 0) {
            unsigned long long taken = 0ull;
            float wsel[TOPK];
            int   isel[TOPK];
            float psum = 0.0f;
            for (int it = 0; it < TOPK; ++it) {
                double best = -1.0e300;
                int    bi   = 0;
                for (int j = 0; j < E; ++j) {
                    if (!((taken >> j) & 1ull)) {
                        const double v = lg[j];
                        if (v > best) { best = v; bi = j; }
                    }
                }
                taken |= 1ull << bi;
                const float p = 1.0f / (1.0f + __expf(-(float)best));
                wsel[it] = p;
                isel[it] = bi;
                psum += p;
            }
            const float inv = 1.0f / psum;
            for (int it = 0; it < TOPK; ++it) {
                weights[(long)row * TOPK + it] = wsel[it] * inv;
                indices[(long)row * TOPK + it] = (float)isel[it];
            }
        }
        __syncthreads();
    }
}

extern "C" void kernel_launch(void* const* d_in, const int* in_sizes, int n_in,
                              void* d_out, int out_size, void* d_ws, size_t ws_size,
                              hipStream_t stream)
{
    const float* A    = (const float*)d_in[0];   // [T, H]
    const float* W    = (const float*)d_in[1];   // [E, H]
    const float* bias = (const float*)d_in[2];   // [E]
    const int T = in_sizes[0] / H;               // 16384

    float* out     = (float*)d_out;
    float* weights = out;                          // [T, 8]
    float* indices = out + (size_t)T * TOPK;       // [T, 8] (float-valued)
    float* probs   = out + (size_t)T * 2 * TOPK;   // [T, 64]

    // workspace: Wt (1 MiB) | flag count (16 B slot) | flag list
    float* Wt = (float*)d_ws;
    const size_t WT_BYTES = (size_t)H * E * sizeof(float);
    int* flagcnt  = (int*)((char*)d_ws + WT_BYTES);
    int* flaglist = flagcnt + 4;
    long cap_l = ((long)ws_size - (long)WT_BYTES - 16) / 4;
    int  cap   = cap_l < 0 ? 0 : (cap_l > T ? T : (int)cap_l);

    hipMemsetAsync(probs, 0, (size_t)T * E * sizeof(float), stream);
    if (cap > 0) hipMemsetAsync(flagcnt, 0, sizeof(int), stream);

    wt_transpose<<<(H * E / 4) / 256, 256, 0, stream>>>(W, Wt);
    router_gemm<<<(T / 64) * NSLICE, 64, 0, stream>>>(A, Wt, probs);
    router_topk<<<T / 64, 64, 0, stream>>>(probs, bias, weights, indices,
                                           flagcnt, flaglist, cap);
    if (cap > 0)
        router_recheck<<<256, 256, 0, stream>>>(A, W, bias, weights, indices,
                                                flagcnt, flaglist, cap);
}

// Round 2
// 1044.203 us; speedup vs baseline: 1.2358x; 1.2358x over previous
//
#include <hip/hip_runtime.h>
#include <math.h>

#define H 4096
#define E 64
#define TOPK 8
#define NSLICE 4             // K split: grid = (T/16)*4 = 4096 one-wave blocks -> 4 waves/SIMD
#define KS (H / NSLICE)      // 1024
#define TAU 1e-4f            // f32 rank-ambiguity threshold (f32 err ~3e-6 rms, 2e-5 worst)

// Fused MoE router:
//   k0: W[E][H] -> Wt[H][E] via LDS tile (coalesced both sides)
//   k1: f32 GEMM, thread = (1 row, 16 experts) => acc[16] (no spill; round-1's
//       acc[64] spilled at VGPR cap 128 -> 524 MB scratch traffic, VALUBusy 6%).
//       Lane map eg*16+rr: w-loads merge 16-way (4 txns/instr, L1-hot Wt),
//       a-loads 16 txns/instr. K sliced 4x, f32 atomicAdd into zeroed probs.
//   k2: +bias, sigmoid in-place, register top-9, flag rows with adjacent
//       top-9 gaps < TAU (f32 order not provably == f64 order).
//   k3: exact-f64 recompute of flagged rows (~100-300), overwrite outputs.
// Workspace: [0,1MiB) Wt ; [1MiB] flag count ; [1MiB+16,...) flag list.

// ---------------- kernel 0: transpose W -> Wt (LDS tile) ----------------
__global__ __launch_bounds__(256) void wt_transpose(
    const float* __restrict__ W, float* __restrict__ Wt)
{
    __shared__ float tile[64][E + 1];
    const int k0 = blockIdx.x * 64;
    const int t  = threadIdx.x;
    const int le = t >> 2;           // expert 0..63
    const int lk = (t & 3) * 16;     // k-chunk base
#pragma unroll
    for (int j = 0; j < 16; j += 4) {
        const float4 v = *(const float4*)(W + (long)le * H + k0 + lk + j);
        tile[lk + j + 0][le] = v.x;
        tile[lk + j + 1][le] = v.y;
        tile[lk + j + 2][le] = v.z;
        tile[lk + j + 3][le] = v.w;
    }
    __syncthreads();
    const int ok = t >> 2;           // k 0..63
    const int oe = (t & 3) * 16;     // expert-chunk base
#pragma unroll
    for (int j = 0; j < 16; j += 4) {
        float4 v;
        v.x = tile[ok][oe + j + 0];
        v.y = tile[ok][oe + j + 1];
        v.z = tile[ok][oe + j + 2];
        v.w = tile[ok][oe + j + 3];
        *(float4*)(Wt + (long)(k0 + ok) * E + oe + j) = v;
    }
}

// ---------------- kernel 1: f32 slice GEMM, acc[16]/thread ----------------
// 16 FMAs per k per thread; 4 w float4 loads per k (merged 16-way across the
// expert-group's lanes); 1 a float4 per 4 k. Live regs ~44 -> no spill.
#define KC(AW, M)                                                         \
    {                                                                     \
        const float4 wv0 = *(const float4*)(wk + (M) * E + 0);            \
        const float4 wv1 = *(const float4*)(wk + (M) * E + 4);            \
        const float4 wv2 = *(const float4*)(wk + (M) * E + 8);            \
        const float4 wv3 = *(const float4*)(wk + (M) * E + 12);           \
        acc[0]  = fmaf((AW), wv0.x, acc[0]);                              \
        acc[1]  = fmaf((AW), wv0.y, acc[1]);                              \
        acc[2]  = fmaf((AW), wv0.z, acc[2]);                              \
        acc[3]  = fmaf((AW), wv0.w, acc[3]);                              \
        acc[4]  = fmaf((AW), wv1.x, acc[4]);                              \
        acc[5]  = fmaf((AW), wv1.y, acc[5]);                              \
        acc[6]  = fmaf((AW), wv1.z, acc[6]);                              \
        acc[7]  = fmaf((AW), wv1.w, acc[7]);                              \
        acc[8]  = fmaf((AW), wv2.x, acc[8]);                              \
        acc[9]  = fmaf((AW), wv2.y, acc[9]);                              \
        acc[10] = fmaf((AW), wv2.z, acc[10]);                             \
        acc[11] = fmaf((AW), wv2.w, acc[11]);                             \
        acc[12] = fmaf((AW), wv3.x, acc[12]);                             \
        acc[13] = fmaf((AW), wv3.y, acc[13]);                             \
        acc[14] = fmaf((AW), wv3.z, acc[14]);                             \
        acc[15] = fmaf((AW), wv3.w, acc[15]);                             \
    }

__global__ __launch_bounds__(64, 4) void router_gemm(
    const float* __restrict__ A, const float* __restrict__ Wt,
    float* __restrict__ logits)
{
    const int ks = blockIdx.x & (NSLICE - 1);
    const int rg = blockIdx.x >> 2;
    const int k0 = ks * KS;
    const int rr = threadIdx.x & 15;   // row within group
    const int eg = threadIdx.x >> 4;   // expert group 0..3
    const long row = (long)rg * 16 + rr;
    const int e0 = eg * 16;

    float acc[16];
#pragma unroll
    for (int j = 0; j < 16; ++j) acc[j] = 0.0f;

    const float* __restrict__ ap = A + row * H + k0;
    const float* __restrict__ wp = Wt + (long)k0 * E + e0;

#pragma unroll 2
    for (int k = 0; k < KS; k += 4) {
        const float4 av = *(const float4*)(ap + k);
        const float* __restrict__ wk = wp + (long)k * E;
        KC(av.x, 0)
        KC(av.y, 1)
        KC(av.z, 2)
        KC(av.w, 3)
    }

    float* out = logits + row * E + e0;   // pre-zeroed; device-scope f32 add
#pragma unroll
    for (int j = 0; j < 16; ++j) atomicAdd(out + j, acc[j]);
}

// ---------------- kernel 2: bias + sigmoid + top-9 + ambiguity flag ----------------
__global__ __launch_bounds__(64) void router_topk(
    float* __restrict__ probs, const float* __restrict__ bias,
    float* __restrict__ weights, float* __restrict__ indices,
    int* __restrict__ flagcnt, int* __restrict__ flaglist, int cap)
{
    const long row = (long)blockIdx.x * 64 + threadIdx.x;
    float* pr = probs + row * E;

    float lg[E];
#pragma unroll
    for (int e = 0; e < E; e += 4) {
        const float4 v = *(const float4*)(pr + e);
        const float4 b = *(const float4*)(bias + e);
        lg[e + 0] = v.x + b.x;
        lg[e + 1] = v.y + b.y;
        lg[e + 2] = v.z + b.z;
        lg[e + 3] = v.w + b.w;
    }

#pragma unroll
    for (int e = 0; e < E; e += 4) {
        float4 o;
        o.x = 1.0f / (1.0f + __expf(-lg[e + 0]));
        o.y = 1.0f / (1.0f + __expf(-lg[e + 1]));
        o.z = 1.0f / (1.0f + __expf(-lg[e + 2]));
        o.w = 1.0f / (1.0f + __expf(-lg[e + 3]));
        *(float4*)(pr + e) = o;
    }

    unsigned long long taken = 0ull;
    float sv[TOPK + 1];
    int   si[TOPK + 1];
#pragma unroll
    for (int it = 0; it <= TOPK; ++it) {
        float best = -3.0e38f;
        int   bi   = 0;
#pragma unroll
        for (int j = 0; j < E; ++j) {
            const bool ok = !((taken >> j) & 1ull) && (lg[j] > best);
            best = ok ? lg[j] : best;
            bi   = ok ? j   : bi;
        }
        sv[it] = best;
        si[it] = bi;
        taken |= 1ull << bi;
    }

    float w8[TOPK];
    float sum = 0.0f;
#pragma unroll
    for (int it = 0; it < TOPK; ++it) {
        w8[it] = 1.0f / (1.0f + __expf(-sv[it]));
        sum += w8[it];
    }
    const float inv = 1.0f / sum;
#pragma unroll
    for (int it = 0; it < TOPK; ++it) {
        weights[row * TOPK + it] = w8[it] * inv;
        indices[row * TOPK + it] = (float)si[it];
    }

    bool amb = false;
#pragma unroll
    for (int it = 0; it < TOPK; ++it) amb |= (sv[it] - sv[it + 1]) < TAU;
    if (amb && cap > 0) {
        const int pos = atomicAdd(flagcnt, 1);
        if (pos < cap) flaglist[pos] = (int)row;
    }
}

// ---------------- kernel 3: exact-f64 recheck of flagged rows ----------------
__global__ __launch_bounds__(256) void router_recheck(
    const float* __restrict__ A, const float* __restrict__ W,
    const float* __restrict__ bias,
    float* __restrict__ weights, float* __restrict__ indices,
    const int* __restrict__ flagcnt, const int* __restrict__ flaglist,
    int cap)
{
    __shared__ double part[4][E];
    __shared__ double lg[E];

    const int e  = threadIdx.x & 63;   // expert
    const int kc = threadIdx.x >> 6;   // k-chunk 0..3

    int n = *flagcnt;
    if (n > cap) n = cap;

    for (int f = blockIdx.x; f < n; f += gridDim.x) {
        const int row = flaglist[f];
        const float* ar = A + (long)row * H + kc * (H / 4);
        const float* wr = W + (long)e   * H + kc * (H / 4);
        double s = 0.0;
        for (int k = 0; k < H / 4; k += 4) {
            const float4 av = *(const float4*)(ar + k);
            const float4 wv = *(const float4*)(wr + k);
            s = fma((double)av.x, (double)wv.x, s);
            s = fma((double)av.y, (double)wv.y, s);
            s = fma((double)av.z, (double)wv.z, s);
            s = fma((double)av.w, (double)wv.w, s);
        }
        part[kc][e] = s;
        __syncthreads();
        if (threadIdx.x < E) {
            const int j = threadIdx.x;
            lg[j] = ((part[0][j] + part[1][j]) + (part[2][j] + part[3][j]))
                    + (double)bias[j];
        }
        __syncthreads();
        if (threadIdx.x == 0) {
            unsigned long long taken = 0ull;
            float wsel[TOPK];
            int   isel[TOPK];
            float psum = 0.0f;
            for (int it = 0; it < TOPK; ++it) {
                double best = -1.0e300;
                int    bi   = 0;
                for (int j = 0; j < E; ++j) {
                    if (!((taken >> j) & 1ull)) {
                        const double v = lg[j];
                        if (v > best) { best = v; bi = j; }
                    }
                }
                taken |= 1ull << bi;
                const float p = 1.0f / (1.0f + __expf(-(float)best));
                wsel[it] = p;
                isel[it] = bi;
                psum += p;
            }
            const float inv = 1.0f / psum;
            for (int it = 0; it < TOPK; ++it) {
                weights[(long)row * TOPK + it] = wsel[it] * inv;
                indices[(long)row * TOPK + it] = (float)isel[it];
            }
        }
        __syncthreads();
    }
}

extern "C" void kernel_launch(void* const* d_in, const int* in_sizes, int n_in,
                              void* d_out, int out_size, void* d_ws, size_t ws_size,
                              hipStream_t stream)
{
    const float* A    = (const float*)d_in[0];   // [T, H]
    const float* W    = (const float*)d_in[1];   // [E, H]
    const float* bias = (const float*)d_in[2];   // [E]
    const int T = in_sizes[0] / H;               // 16384

    float* out     = (float*)d_out;
    float* weights = out;                          // [T, 8]
    float* indices = out + (size_t)T * TOPK;       // [T, 8] (float-valued)
    float* probs   = out + (size_t)T * 2 * TOPK;   // [T, 64]

    float* Wt = (float*)d_ws;
    const size_t WT_BYTES = (size_t)H * E * sizeof(float);
    int* flagcnt  = (int*)((char*)d_ws + WT_BYTES);
    int* flaglist = flagcnt + 4;
    long cap_l = ((long)ws_size - (long)WT_BYTES - 16) / 4;
    int  cap   = cap_l < 0 ? 0 : (cap_l > T ? T : (int)cap_l);

    hipMemsetAsync(probs, 0, (size_t)T * E * sizeof(float), stream);
    if (cap > 0) hipMemsetAsync(flagcnt, 0, sizeof(int), stream);

    wt_transpose<<<H / 64, 256, 0, stream>>>(W, Wt);
    router_gemm<<<(T / 16) * NSLICE, 64, 0, stream>>>(A, Wt, probs);
    router_topk<<<T / 64, 64, 0, stream>>>(probs, bias, weights, indices,
                                           flagcnt, flaglist, cap);
    if (cap > 0)
        router_recheck<<<256, 256, 0, stream>>>(A, W, bias, weights, indices,
                                                flagcnt, flaglist, cap);
}

// Round 3
// 483.101 us; speedup vs baseline: 2.6710x; 2.1615x over previous
//
#include <hip/hip_runtime.h>
#include <math.h>

#define H 4096
#define E 64
#define TOPK 8
#define NSLICE 4             // K split: grid = (T/64)*4 = 1024 blocks -> 4 blocks/CU
#define KS (H / NSLICE)      // 1024 k per block
#define BK 32                // staged K-tile
#define BM 64                // rows per block
#define TAU 1e-4f            // f32 rank-ambiguity threshold (f32 err ~1e-5 worst)

// Fused MoE router, round-3:
//   k1: f32 LDS-tiled GEMM (round-0 structure: 4x4 microtile, reg-prefetch
//       double buffer) with K split 4x for occupancy (round 0 ran 1 block/CU,
//       nothing overlapped; round 2's global-outer-product was VMEM-latency
//       bound at VALUBusy 8%). f32 atomicAdd partials into zeroed probs buf.
//   k2: +bias, sigmoid in-place, register top-9, flag rows with adjacent
//       top-9 gaps < TAU (f32 order not provably == f64 order there).
//   k3: exact-f64 recompute of flagged rows (~150), overwrite outputs.
// Workspace: [0] flag count ; [16,...) flag list.

// ---------------- kernel 1: f32 K-sliced LDS-tiled GEMM ----------------
__global__ __launch_bounds__(256, 4) void router_gemm(
    const float* __restrict__ A, const float* __restrict__ W,
    float* __restrict__ logits)
{
    __shared__ float Alds[BM][BK + 4];   // stride 36 floats: 16B-aligned rows
    __shared__ float Wlds[BK][E];        // k-major

    const int tid = threadIdx.x;
    const int rg  = blockIdx.x >> 2;     // row group 0..255
    const int ks  = blockIdx.x & 3;      // K slice 0..3
    const long row0 = (long)rg * BM;
    const int  k0   = ks * KS;

    // staging maps
    const int arow = tid >> 2;           // 0..63
    const int aseg = tid & 3;            // 8 floats each
    const int we   = tid & 63;           // expert row of W
    const int wk   = tid >> 6;           // 0..3 -> k-chunk of 8

    // compute map (round-0 4x4 microtile)
    const int er = tid & 15;             // experts [4*er, 4*er+4)
    const int rr = tid >> 4;             // rows    [4*rr, 4*rr+4)

    float acc[4][4];
#pragma unroll
    for (int i = 0; i < 4; ++i)
#pragma unroll
        for (int j = 0; j < 4; ++j) acc[i][j] = 0.0f;

    // register prefetch of tile 0
    const float* ap = A + (row0 + arow) * H + k0 + aseg * 8;
    const float* wp = W + (long)we * H + k0 + wk * 8;
    float4 pa0 = *(const float4*)(ap + 0);
    float4 pa1 = *(const float4*)(ap + 4);
    float4 pw0 = *(const float4*)(wp + 0);
    float4 pw1 = *(const float4*)(wp + 4);

    for (int kt = 0; kt < KS; kt += BK) {
        // write prefetched tile to LDS
        *(float4*)&Alds[arow][aseg * 8 + 0] = pa0;
        *(float4*)&Alds[arow][aseg * 8 + 4] = pa1;
        {
            const int kb = wk * 8;
            Wlds[kb + 0][we] = pw0.x;
            Wlds[kb + 1][we] = pw0.y;
            Wlds[kb + 2][we] = pw0.z;
            Wlds[kb + 3][we] = pw0.w;
            Wlds[kb + 4][we] = pw1.x;
            Wlds[kb + 5][we] = pw1.y;
            Wlds[kb + 6][we] = pw1.z;
            Wlds[kb + 7][we] = pw1.w;
        }
        __syncthreads();

        // issue next-tile loads; stay in flight across the FMA block
        if (kt + BK < KS) {
            const int kn = k0 + kt + BK;
            const float* apn = A + (row0 + arow) * H + kn + aseg * 8;
            const float* wpn = W + (long)we * H + kn + wk * 8;
            pa0 = *(const float4*)(apn + 0);
            pa1 = *(const float4*)(apn + 4);
            pw0 = *(const float4*)(wpn + 0);
            pw1 = *(const float4*)(wpn + 4);
        }

#pragma unroll
        for (int kk = 0; kk < BK; kk += 4) {
            float4 a[4];   // [row i] covering k..k+3
            float4 w[4];   // [k m]   covering 4 experts
#pragma unroll
            for (int i = 0; i < 4; ++i)
                a[i] = *(const float4*)&Alds[rr * 4 + i][kk];
#pragma unroll
            for (int m = 0; m < 4; ++m)
                w[m] = *(const float4*)&Wlds[kk + m][er * 4];
#pragma unroll
            for (int i = 0; i < 4; ++i) {
                const float* av = (const float*)&a[i];
#pragma unroll
                for (int m = 0; m < 4; ++m) {
                    const float* wv = (const float*)&w[m];
                    acc[i][0] = fmaf(av[m], wv[0], acc[i][0]);
                    acc[i][1] = fmaf(av[m], wv[1], acc[i][1]);
                    acc[i][2] = fmaf(av[m], wv[2], acc[i][2]);
                    acc[i][3] = fmaf(av[m], wv[3], acc[i][3]);
                }
            }
        }
        __syncthreads();
    }

    // partial-sum into pre-zeroed probs (device-scope f32 atomics)
#pragma unroll
    for (int i = 0; i < 4; ++i) {
        float* out = logits + (row0 + rr * 4 + i) * E + er * 4;
        atomicAdd(out + 0, acc[i][0]);
        atomicAdd(out + 1, acc[i][1]);
        atomicAdd(out + 2, acc[i][2]);
        atomicAdd(out + 3, acc[i][3]);
    }
}

// ---------------- kernel 2: bias + sigmoid + top-9 + ambiguity flag ----------------
__global__ __launch_bounds__(64) void router_topk(
    float* __restrict__ probs, const float* __restrict__ bias,
    float* __restrict__ weights, float* __restrict__ indices,
    int* __restrict__ flagcnt, int* __restrict__ flaglist, int cap)
{
    const long row = (long)blockIdx.x * 64 + threadIdx.x;
    float* pr = probs + row * E;

    float lg[E];
#pragma unroll
    for (int e = 0; e < E; e += 4) {
        const float4 v = *(const float4*)(pr + e);
        const float4 b = *(const float4*)(bias + e);
        lg[e + 0] = v.x + b.x;
        lg[e + 1] = v.y + b.y;
        lg[e + 2] = v.z + b.z;
        lg[e + 3] = v.w + b.w;
    }

#pragma unroll
    for (int e = 0; e < E; e += 4) {
        float4 o;
        o.x = 1.0f / (1.0f + __expf(-lg[e + 0]));
        o.y = 1.0f / (1.0f + __expf(-lg[e + 1]));
        o.z = 1.0f / (1.0f + __expf(-lg[e + 2]));
        o.w = 1.0f / (1.0f + __expf(-lg[e + 3]));
        *(float4*)(pr + e) = o;
    }

    unsigned long long taken = 0ull;
    float sv[TOPK + 1];
    int   si[TOPK + 1];
#pragma unroll
    for (int it = 0; it <= TOPK; ++it) {
        float best = -3.0e38f;
        int   bi   = 0;
#pragma unroll
        for (int j = 0; j < E; ++j) {
            const bool ok = !((taken >> j) & 1ull) && (lg[j] > best);
            best = ok ? lg[j] : best;
            bi   = ok ? j   : bi;
        }
        sv[it] = best;
        si[it] = bi;
        taken |= 1ull << bi;
    }

    float w8[TOPK];
    float sum = 0.0f;
#pragma unroll
    for (int it = 0; it < TOPK; ++it) {
        w8[it] = 1.0f / (1.0f + __expf(-sv[it]));
        sum += w8[it];
    }
    const float inv = 1.0f / sum;
#pragma unroll
    for (int it = 0; it < TOPK; ++it) {
        weights[row * TOPK + it] = w8[it] * inv;
        indices[row * TOPK + it] = (float)si[it];
    }

    bool amb = false;
#pragma unroll
    for (int it = 0; it < TOPK; ++it) amb |= (sv[it] - sv[it + 1]) < TAU;
    if (amb && cap > 0) {
        const int pos = atomicAdd(flagcnt, 1);
        if (pos < cap) flaglist[pos] = (int)row;
    }
}

// ---------------- kernel 3: exact-f64 recheck of flagged rows ----------------
__global__ __launch_bounds__(256) void router_recheck(
    const float* __restrict__ A, const float* __restrict__ W,
    const float* __restrict__ bias,
    float* __restrict__ weights, float* __restrict__ indices,
    const int* __restrict__ flagcnt, const int* __restrict__ flaglist,
    int cap)
{
    __shared__ double part[4][E];
    __shared__ double lg[E];

    const int e  = threadIdx.x & 63;   // expert
    const int kc = threadIdx.x >> 6;   // k-chunk 0..3

    int n = *flagcnt;
    if (n > cap) n = cap;

    for (int f = blockIdx.x; f < n; f += gridDim.x) {
        const int row = flaglist[f];
        const float* ar = A + (long)row * H + kc * (H / 4);
        const float* wr = W + (long)e   * H + kc * (H / 4);
        double s = 0.0;
        for (int k = 0; k < H / 4; k += 4) {
            const float4 av = *(const float4*)(ar + k);
            const float4 wv = *(const float4*)(wr + k);
            s = fma((double)av.x, (double)wv.x, s);
            s = fma((double)av.y, (double)wv.y, s);
            s = fma((double)av.z, (double)wv.z, s);
            s = fma((double)av.w, (double)wv.w, s);
        }
        part[kc][e] = s;
        __syncthreads();
        if (threadIdx.x < E) {
            const int j = threadIdx.x;
            lg[j] = ((part[0][j] + part[1][j]) + (part[2][j] + part[3][j]))
                    + (double)bias[j];
        }
        __syncthreads();
        if (threadIdx.x == 0) {
            unsigned long long taken = 0ull;
            float wsel[TOPK];
            int   isel[TOPK];
            float psum = 0.0f;
            for (int it = 0; it < TOPK; ++it) {
                double best = -1.0e300;
                int    bi   = 0;
                for (int j = 0; j < E; ++j) {
                    if (!((taken >> j) & 1ull)) {
                        const double v = lg[j];
                        if (v > best) { best = v; bi = j; }
                    }
                }
                taken |= 1ull << bi;
                const float p = 1.0f / (1.0f + __expf(-(float)best));
                wsel[it] = p;
                isel[it] = bi;
                psum += p;
            }
            const float inv = 1.0f / psum;
            for (int it = 0; it < TOPK; ++it) {
                weights[(long)row * TOPK + it] = wsel[it] * inv;
                indices[(long)row * TOPK + it] = (float)isel[it];
            }
        }
        __syncthreads();
    }
}

extern "C" void kernel_launch(void* const* d_in, const int* in_sizes, int n_in,
                              void* d_out, int out_size, void* d_ws, size_t ws_size,
                              hipStream_t stream)
{
    const float* A    = (const float*)d_in[0];   // [T, H]
    const float* W    = (const float*)d_in[1];   // [E, H]
    const float* bias = (const float*)d_in[2];   // [E]
    const int T = in_sizes[0] / H;               // 16384

    float* out     = (float*)d_out;
    float* weights = out;                          // [T, 8]
    float* indices = out + (size_t)T * TOPK;       // [T, 8] (float-valued)
    float* probs   = out + (size_t)T * 2 * TOPK;   // [T, 64]

    int* flagcnt  = (int*)d_ws;
    int* flaglist = flagcnt + 4;
    long cap_l = ((long)ws_size - 16) / 4;
    int  cap   = cap_l < 0 ? 0 : (cap_l > T ? T : (int)cap_l);

    hipMemsetAsync(probs, 0, (size_t)T * E * sizeof(float), stream);
    if (cap > 0) hipMemsetAsync(flagcnt, 0, sizeof(int), stream);

    router_gemm<<<(T / BM) * NSLICE, 256, 0, stream>>>(A, W, probs);
    router_topk<<<T / 64, 64, 0, stream>>>(probs, bias, weights, indices,
                                           flagcnt, flaglist, cap);
    if (cap > 0)
        router_recheck<<<256, 256, 0, stream>>>(A, W, bias, weights, indices,
                                                flagcnt, flaglist, cap);
}

// Round 5
// 482.056 us; speedup vs baseline: 2.6768x; 1.0022x over previous
//
#include <hip/hip_runtime.h>
#include <math.h>

#define H 4096
#define E 64
#define TOPK 8
#define BM 64               // rows per block
#define BK 64               // K-tile (48.6 KB LDS total)
#define NKSTEP (BK / 32)    // MFMA k-steps per tile = 2
#define NTILE (H / BK)      // 64
#define TAU 1e-4f           // 4-pass split-bf16 == f32-FMA accuracy class (r1-r3 validated)

// Fused MoE router, round-5 (round-4 resubmit, hardened):
//   Logits via 4-pass split-bf16 MFMA: a=ah+al, w=wh+wl;
//   acc += ah*wh + ah*wl + al*wh + al*wl. Residual error ~1e-6 (representation
//   only) == the f32-VALU path that validated TAU=1e-4 in rounds 1-3.
//   Full K per block -> no atomics, no probs memset; topk fused in epilogue.
//   A-stream HBM floor ~43 us.
//   k0: W f32 -> Whi/Wlo bf16 workspace (1 MB, L2-resident)
//   k1: MFMA gemm + bias + sigmoid + probs + top-9 + TAU flag (256 x 512thr)
//   k2: exact-f64 recheck of flagged rows (~150 at TAU=1e-4)
// Workspace: [0,512K) Whi ; [512K,1M) Wlo ; [1M] flagcnt ; [1M+16,..) flaglist.

typedef __attribute__((ext_vector_type(8))) short bf16x8;
typedef __attribute__((ext_vector_type(4))) float f32x4;

__device__ __forceinline__ unsigned short bf16_rne(float x) {
    unsigned int u = __float_as_uint(x);
    u += 0x7FFFu + ((u >> 16) & 1u);
    return (unsigned short)(u >> 16);
}
__device__ __forceinline__ float bf16_f32(unsigned short h) {
    return __uint_as_float(((unsigned int)h) << 16);
}

// pack two f32 into bf16x2 hi + bf16x2 lo dwords
#define SPLIT2(F0, F1, HI, LO)                                          \
    {                                                                   \
        const unsigned short h0 = bf16_rne(F0), h1 = bf16_rne(F1);      \
        const unsigned short l0 = bf16_rne((F0) - bf16_f32(h0));        \
        const unsigned short l1 = bf16_rne((F1) - bf16_f32(h1));        \
        HI = (unsigned int)h0 | ((unsigned int)h1 << 16);               \
        LO = (unsigned int)l0 | ((unsigned int)l1 << 16);               \
    }

// ---------------- kernel 0: W f32 -> bf16 hi/lo split ----------------
__global__ __launch_bounds__(256) void w_split(
    const float* __restrict__ W, unsigned short* __restrict__ Whi,
    unsigned short* __restrict__ Wlo)
{
    const size_t t = (size_t)blockIdx.x * 256 + threadIdx.x;  // 65536 threads x 4
    const float4 v = *(const float4*)(W + t * 4);
    uint2 h, l;
    SPLIT2(v.x, v.y, h.x, l.x);
    SPLIT2(v.z, v.w, h.y, l.y);
    *(uint2*)(Whi + t * 4) = h;
    *(uint2*)(Wlo + t * 4) = l;
}

// ---------------- kernel 1: split-bf16 MFMA GEMM + fused topk ----------------
__global__ __launch_bounds__(512, 2) void router_gemm_topk(
    const float* __restrict__ A, const unsigned short* __restrict__ Whi,
    const unsigned short* __restrict__ Wlo, const float* __restrict__ bias,
    float* __restrict__ weights, float* __restrict__ indices,
    float* __restrict__ probs,
    int* __restrict__ flagcnt, int* __restrict__ flaglist, int cap)
{
    // 16B-slot XOR swizzle (slot ^ (row&7)) on both write and read sides:
    // row stride 128 B would otherwise put frag-read lanes in few banks.
    __shared__ unsigned short Ahi[BM][BK];   // 8 KB each
    __shared__ unsigned short Alo[BM][BK];
    __shared__ unsigned short Bhi[E][BK];
    __shared__ unsigned short Blo[E][BK];
    __shared__ float Llds[BM][E + 1];        // f32 logits for topk (16.6 KB)

    const int tid = threadIdx.x;
    const long row0 = (long)blockIdx.x * BM;

    // ---- staging map: 512 threads; row/expert = tid>>3, 8-elem k-seg = tid&7
    const int srow = tid >> 3;
    const int sseg = tid & 7;
    const int slot = (sseg ^ (srow & 7)) * 8;            // ushort offset in row

    const float* __restrict__ ap          = A   + (row0 + srow) * H + sseg * 8;
    const unsigned short* __restrict__ wh = Whi + (size_t)srow * H + sseg * 8;
    const unsigned short* __restrict__ wl = Wlo + (size_t)srow * H + sseg * 8;

    // ---- compute map: 8 waves; wave = 16 rows x 32 experts (2 MFMA col-tiles)
    const int wv    = tid >> 6;
    const int l     = tid & 63;
    const int rbase = (wv & 3) * 16;
    const int cbase = (wv >> 2) * 32;
    const int lrow  = l & 15;
    const int khalf = l >> 4;            // 8-elem k-group within 32-k step

    f32x4 acc0 = {0.f, 0.f, 0.f, 0.f};
    f32x4 acc1 = {0.f, 0.f, 0.f, 0.f};

    // ---- prologue: prefetch tile 0 into registers
    float4 pa0 = *(const float4*)(ap + 0);
    float4 pa1 = *(const float4*)(ap + 4);
    uint4  pbh = *(const uint4*)(wh);
    uint4  pbl = *(const uint4*)(wl);

    for (int t = 0; t < NTILE; ++t) {
        // split A to bf16 hi/lo and store staged tile
        uint4 h, lo;
        SPLIT2(pa0.x, pa0.y, h.x, lo.x);
        SPLIT2(pa0.z, pa0.w, h.y, lo.y);
        SPLIT2(pa1.x, pa1.y, h.z, lo.z);
        SPLIT2(pa1.z, pa1.w, h.w, lo.w);
        *(uint4*)(&Ahi[srow][slot]) = h;
        *(uint4*)(&Alo[srow][slot]) = lo;
        *(uint4*)(&Bhi[srow][slot]) = pbh;
        *(uint4*)(&Blo[srow][slot]) = pbl;
        __syncthreads();

        // issue next-tile loads; they stay in flight across the MFMA block
        if (t + 1 < NTILE) {
            const int kn = (t + 1) * BK;
            pa0 = *(const float4*)(ap + kn + 0);
            pa1 = *(const float4*)(ap + kn + 4);
            pbh = *(const uint4*)(wh + kn);
            pbl = *(const uint4*)(wl + kn);
        }

#pragma unroll
        for (int s = 0; s < NKSTEP; ++s) {
            const int fs = ((s * 4 + khalf) ^ (lrow & 7)) * 8;
            const bf16x8 fah  = *(const bf16x8*)(&Ahi[rbase + lrow][fs]);
            const bf16x8 fal  = *(const bf16x8*)(&Alo[rbase + lrow][fs]);
            const bf16x8 fbh0 = *(const bf16x8*)(&Bhi[cbase + lrow][fs]);
            const bf16x8 fbl0 = *(const bf16x8*)(&Blo[cbase + lrow][fs]);
            const bf16x8 fbh1 = *(const bf16x8*)(&Bhi[cbase + 16 + lrow][fs]);
            const bf16x8 fbl1 = *(const bf16x8*)(&Blo[cbase + 16 + lrow][fs]);
            acc0 = __builtin_amdgcn_mfma_f32_16x16x32_bf16(fah, fbh0, acc0, 0, 0, 0);
            acc0 = __builtin_amdgcn_mfma_f32_16x16x32_bf16(fah, fbl0, acc0, 0, 0, 0);
            acc0 = __builtin_amdgcn_mfma_f32_16x16x32_bf16(fal, fbh0, acc0, 0, 0, 0);
            acc0 = __builtin_amdgcn_mfma_f32_16x16x32_bf16(fal, fbl0, acc0, 0, 0, 0);
            acc1 = __builtin_amdgcn_mfma_f32_16x16x32_bf16(fah, fbh1, acc1, 0, 0, 0);
            acc1 = __builtin_amdgcn_mfma_f32_16x16x32_bf16(fah, fbl1, acc1, 0, 0, 0);
            acc1 = __builtin_amdgcn_mfma_f32_16x16x32_bf16(fal, fbh1, acc1, 0, 0, 0);
            acc1 = __builtin_amdgcn_mfma_f32_16x16x32_bf16(fal, fbl1, acc1, 0, 0, 0);
        }
        __syncthreads();
    }

    // ---- epilogue: logits (+bias) -> LDS
    {
        const int c0 = cbase + lrow;
        const int c1 = cbase + 16 + lrow;
        const float b0 = bias[c0], b1 = bias[c1];
#pragma unroll
        for (int r = 0; r < 4; ++r) {
            const int row = rbase + khalf * 4 + r;   // C/D: row=(lane>>4)*4+reg
            Llds[row][c0] = acc0[r] + b0;
            Llds[row][c1] = acc1[r] + b1;
        }
    }
    __syncthreads();

    // coalesced probs write: row = tid>>3, 8 experts per thread
    {
        const int row = tid >> 3;
        const int c   = (tid & 7) * 8;
        float4 o0, o1;
        o0.x = 1.0f / (1.0f + __expf(-Llds[row][c + 0]));
        o0.y = 1.0f / (1.0f + __expf(-Llds[row][c + 1]));
        o0.z = 1.0f / (1.0f + __expf(-Llds[row][c + 2]));
        o0.w = 1.0f / (1.0f + __expf(-Llds[row][c + 3]));
        o1.x = 1.0f / (1.0f + __expf(-Llds[row][c + 4]));
        o1.y = 1.0f / (1.0f + __expf(-Llds[row][c + 5]));
        o1.z = 1.0f / (1.0f + __expf(-Llds[row][c + 6]));
        o1.w = 1.0f / (1.0f + __expf(-Llds[row][c + 7]));
        *(float4*)(probs + (row0 + row) * E + c + 0) = o0;
        *(float4*)(probs + (row0 + row) * E + c + 4) = o1;
    }

    // top-9 per row (threads 0..63); strict > => lowest idx on ties
    if (tid < BM) {
        const int r = tid;
        unsigned long long taken = 0ull;
        float sv[TOPK + 1];
        int   si[TOPK + 1];
#pragma unroll
        for (int it = 0; it <= TOPK; ++it) {
            float best = -3.0e38f;
            int   bi   = 0;
            for (int j = 0; j < E; ++j) {
                if (!((taken >> j) & 1ull)) {
                    const float v = Llds[r][j];
                    if (v > best) { best = v; bi = j; }
                }
            }
            taken |= 1ull << bi;
            sv[it] = best;
            si[it] = bi;
        }
        float w8[TOPK];
        float sum = 0.0f;
#pragma unroll
        for (int it = 0; it < TOPK; ++it) {
            w8[it] = 1.0f / (1.0f + __expf(-sv[it]));
            sum += w8[it];
        }
        const float inv = 1.0f / sum;
#pragma unroll
        for (int it = 0; it < TOPK; ++it) {
            weights[(row0 + r) * TOPK + it] = w8[it] * inv;
            indices[(row0 + r) * TOPK + it] = (float)si[it];
        }
        bool amb = false;
#pragma unroll
        for (int it = 0; it < TOPK; ++it) amb |= (sv[it] - sv[it + 1]) < TAU;
        if (amb && cap > 0) {
            const int pos = atomicAdd(flagcnt, 1);
            if (pos < cap) flaglist[pos] = (int)(row0 + r);
        }
    }
}

// ---------------- kernel 2: exact-f64 recheck of flagged rows ----------------
__global__ __launch_bounds__(256) void router_recheck(
    const float* __restrict__ A, const float* __restrict__ W,
    const float* __restrict__ bias,
    float* __restrict__ weights, float* __restrict__ indices,
    const int* __restrict__ flagcnt, const int* __restrict__ flaglist,
    int cap)
{
    __shared__ double part[4][E];
    __shared__ double lg[E];

    const int e  = threadIdx.x & 63;   // expert
    const int kc = threadIdx.x >> 6;   // k-chunk 0..3

    int n = *flagcnt;
    if (n > cap) n = cap;

    for (int f = blockIdx.x; f < n; f += gridDim.x) {
        const int row = flaglist[f];
        const float* ar = A + (long)row * H + kc * (H / 4);
        const float* wr = W + (long)e   * H + kc * (H / 4);
        double s = 0.0;
        for (int k = 0; k < H / 4; k += 4) {
            const float4 av = *(const float4*)(ar + k);
            const float4 wv = *(const float4*)(wr + k);
            s = fma((double)av.x, (double)wv.x, s);
            s = fma((double)av.y, (double)wv.y, s);
            s = fma((double)av.z, (double)wv.z, s);
            s = fma((double)av.w, (double)wv.w, s);
        }
        part[kc][e] = s;
        __syncthreads();
        if (threadIdx.x < E) {
            const int j = threadIdx.x;
            lg[j] = ((part[0][j] + part[1][j]) + (part[2][j] + part[3][j]))
                    + (double)bias[j];
        }
        __syncthreads();
        if (threadIdx.x == 0) {
            unsigned long long taken = 0ull;
            float wsel[TOPK];
            int   isel[TOPK];
            float psum = 0.0f;
            for (int it = 0; it < TOPK; ++it) {
                double best = -1.0e300;
                int    bi   = 0;
                for (int j = 0; j < E; ++j) {
                    if (!((taken >> j) & 1ull)) {
                        const double v = lg[j];
                        if (v > best) { best = v; bi = j; }
                    }
                }
                taken |= 1ull << bi;
                const float p = 1.0f / (1.0f + __expf(-(float)best));
                wsel[it] = p;
                isel[it] = bi;
                psum += p;
            }
            const float inv = 1.0f / psum;
            for (int it = 0; it < TOPK; ++it) {
                weights[(long)row * TOPK + it] = wsel[it] * inv;
                indices[(long)row * TOPK + it] = (float)isel[it];
            }
        }
        __syncthreads();
    }
}

extern "C" void kernel_launch(void* const* d_in, const int* in_sizes, int n_in,
                              void* d_out, int out_size, void* d_ws, size_t ws_size,
                              hipStream_t stream)
{
    const float* A    = (const float*)d_in[0];   // [T, H]
    const float* W    = (const float*)d_in[1];   // [E, H]
    const float* bias = (const float*)d_in[2];   // [E]
    const int T = in_sizes[0] / H;               // 16384

    float* out     = (float*)d_out;
    float* weights = out;                          // [T, 8]
    float* indices = out + (size_t)T * TOPK;       // [T, 8] (float-valued)
    float* probs   = out + (size_t)T * 2 * TOPK;   // [T, 64]

    unsigned short* Whi = (unsigned short*)d_ws;           // 512 KB
    unsigned short* Wlo = Whi + (size_t)E * H;             // 512 KB
    const size_t W_BYTES = (size_t)E * H * 2 * sizeof(unsigned short);
    int* flagcnt  = (int*)((char*)d_ws + W_BYTES);
    int* flaglist = flagcnt + 4;
    long cap_l = ((long)ws_size - (long)W_BYTES - 16) / 4;
    int  cap   = cap_l < 0 ? 0 : (cap_l > T ? T : (int)cap_l);

    if (cap > 0) hipMemsetAsync(flagcnt, 0, sizeof(int), stream);

    w_split<<<(E * H / 4) / 256, 256, 0, stream>>>(W, Whi, Wlo);
    router_gemm_topk<<<T / BM, 512, 0, stream>>>(A, Whi, Wlo, bias,
                                                 weights, indices, probs,
                                                 flagcnt, flaglist, cap);
    if (cap > 0)
        router_recheck<<<256, 256, 0, stream>>>(A, W, bias, weights, indices,
                                                flagcnt, flaglist, cap);
}